// Round 1
// baseline (111870.972 us; speedup 1.0000x reference)
//
#include <hip/hip_runtime.h>
#include <hip/hip_fp16.h>
#include <cstdint>
#include <cstddef>

#define H   1024
#define V   32000
#define L   2048
#define G4  4096      // 4*H
#define NB  256       // blocks (1 per CU, co-resident: <=128 VGPR, ~9KB LDS)
#define NT  1024      // threads per block (16 waves of 64)
#define RPB (V / NB)  // 125 FC rows per block

// ---------------------------------------------------------------------------
__device__ __forceinline__ float wave_reduce_sum(float v) {
    #pragma unroll
    for (int off = 32; off > 0; off >>= 1) v += __shfl_down(v, off);
    return v;
}

__device__ __forceinline__ float wave_reduce_max(float v) {
    #pragma unroll
    for (int off = 32; off > 0; off >>= 1) v = fmaxf(v, __shfl_down(v, off));
    return v;
}

__device__ __forceinline__ unsigned long long wave_reduce_max_u64(unsigned long long v) {
    #pragma unroll
    for (int off = 32; off > 0; off >>= 1) {
        const unsigned long long o = __shfl_down(v, off);
        v = (o > v) ? o : v;
    }
    return v;
}

__device__ __forceinline__ float sigmoidf_(float x) {
    return 1.0f / (1.0f + expf(-x));
}

__device__ __forceinline__ float dot4(const float4 w, const float* __restrict__ h, int c) {
    return w.x * h[c] + w.y * h[c + 1] + w.z * h[c + 2] + w.w * h[c + 3];
}

// ---------------------------------------------------------------------------
// Device-scope sense-reversing grid barrier.
// AGENT-scope atomics are mandatory: they emit sc1 cache ops that cross the
// per-XCD L2 boundary (volatile spin would read a stale L2 line forever).
// __threadfence() provides the release (writeback) / acquire (invalidate)
// for the regular data stores/loads around the barrier.
// ---------------------------------------------------------------------------
__device__ __forceinline__ void grid_sync(unsigned int* __restrict__ cnt,
                                          unsigned int* __restrict__ gen)
{
    __syncthreads();
    if (threadIdx.x == 0) {
        __threadfence();  // release: flush this block's global writes
        const unsigned int g =
            __hip_atomic_load(gen, __ATOMIC_RELAXED, __HIP_MEMORY_SCOPE_AGENT);
        const unsigned int a =
            __hip_atomic_fetch_add(cnt, 1u, __ATOMIC_ACQ_REL, __HIP_MEMORY_SCOPE_AGENT);
        if (a == NB - 1u) {
            __hip_atomic_store(cnt, 0u, __ATOMIC_RELAXED, __HIP_MEMORY_SCOPE_AGENT);
            __hip_atomic_store(gen, g + 1u, __ATOMIC_RELEASE, __HIP_MEMORY_SCOPE_AGENT);
        } else {
            while (__hip_atomic_load(gen, __ATOMIC_RELAXED, __HIP_MEMORY_SCOPE_AGENT) == g) {
                __builtin_amdgcn_s_sleep(1);
            }
        }
        __threadfence();  // acquire: invalidate L1/L2 so remote writes are seen
    }
    __syncthreads();
}

// ---------------------------------------------------------------------------
// One-time (per launch): w_fc fp32 -> fp16 in workspace
// ---------------------------------------------------------------------------
__global__ __launch_bounds__(256) void convert_fc(
    const float* __restrict__ src, __half* __restrict__ dst, int n2)
{
    const int stride = gridDim.x * blockDim.x;
    for (int i = blockIdx.x * blockDim.x + threadIdx.x; i < n2; i += stride) {
        const float2 f = ((const float2*)src)[i];
        ((__half2*)dst)[i] = __floats2half2_rn(f.x, f.y);
    }
}

// ---------------------------------------------------------------------------
// Persistent fused kernel: init + 2047 x { phaseA (lstm) | phaseB (fc) }
// with 2 grid barriers per step instead of 2 kernel launches per step.
// Numerics identical to the 2-kernel baseline (same summation orders).
// ---------------------------------------------------------------------------
__global__ __launch_bounds__(NT) void persistent_kernel(
    const int* __restrict__ y, const float* __restrict__ ctx,
    const float* __restrict__ w_ih0, const float* __restrict__ w_hh0,
    const float* __restrict__ b_ih0, const float* __restrict__ b_hh0,
    const float* __restrict__ w_ih1, const float* __restrict__ w_hh1,
    const float* __restrict__ b_ih1, const float* __restrict__ b_hh1,
    const float* __restrict__ w_fc, const __half* __restrict__ wfc16,
    const float* __restrict__ b_fc,
    float* __restrict__ v0g, float* __restrict__ u1,
    float* __restrict__ h1g, unsigned long long* __restrict__ keys,
    unsigned int* __restrict__ bar, float* __restrict__ out, const int use16)
{
    __shared__ __align__(16) float h0s[H];
    __shared__ __align__(16) float h1s[H];
    __shared__ float g1s[16];
    __shared__ float aprx[128];
    __shared__ float Amax_s;
    __shared__ unsigned long long kred[4];
    __shared__ unsigned long long wkey[16];
    __shared__ float c1s[4];

    const int b = blockIdx.x, t = threadIdx.x;
    const int wave = t >> 6, lane = t & 63;
    const int rowR = (wave >> 2) * H + b * 4 + (wave & 3);

    unsigned int* cnt = bar;        // cacheline 0
    unsigned int* gen = bar + 32;   // cacheline 2 (byte offset 128)

    // c0 element t lives in a register, redundantly per block.
    float c0_reg = ctx[t];

    // ---------------- prologue (former init_kernel) ----------------
    {
        h0s[t] = ctx[t];
        h1s[t] = ctx[H + t];
        if (t < 4) c1s[t] = ctx[H + b * 4 + t];
        __syncthreads();

        const float* w0r = w_hh0 + (size_t)rowR * H;
        const float* w1r = w_hh1 + (size_t)rowR * H;
        float accV = 0.f, accU = 0.f;
        #pragma unroll
        for (int k = 0; k < 4; k++) {
            const int c = k * 256 + lane * 4;
            accV += dot4(*(const float4*)(w0r + c), h0s, c);
            accU += dot4(*(const float4*)(w1r + c), h1s, c);
        }
        accV = wave_reduce_sum(accV);
        accU = wave_reduce_sum(accU);
        if (lane == 0) {
            v0g[rowR] = accV + b_ih0[rowR] + b_hh0[rowR];   // buffer 0
            u1[rowR]  = accU + b_ih1[rowR] + b_hh1[rowR];
        }
        if (b == 0) {
            h1g[t] = ctx[H + t];
            if (t < NB) keys[t] = 0ull;
            if (t == 0) {
                keys[0] = ((unsigned long long)0x7F800000u << 32) |
                          (0xFFFFFFFFu - (unsigned int)y[0]);
            }
        }
    }
    grid_sync(cnt, gen);

    // ---------------- main loop ----------------
    for (int step = 1; step < L; ++step) {
        // ================= phase A: lstm =================
        const float* v0i = v0g + ((step - 1) & 1) * G4;
        float*       v0o = v0g + (step & 1) * G4;

        // argmax finalize over 256 block keys (block-redundant)
        if (wave < 4) {
            unsigned long long k = keys[t];              // t < 256
            k = wave_reduce_max_u64(k);
            if (lane == 0) kred[wave] = k;
        }
        __syncthreads();
        unsigned long long kk = kred[0];
        kk = (kred[1] > kk) ? kred[1] : kk;
        kk = (kred[2] > kk) ? kred[2] : kk;
        kk = (kred[3] > kk) ? kred[3] : kk;
        const float tok =
            (float)(unsigned int)(0xFFFFFFFFu - (unsigned int)(kk & 0xFFFFFFFFull));

        // cell0 (block-redundant), element j = t; c0 in register
        {
            const float gi = v0i[t]         + tok * w_ih0[t];
            const float gf = v0i[H + t]     + tok * w_ih0[H + t];
            const float gg = v0i[2 * H + t] + tok * w_ih0[2 * H + t];
            const float go = v0i[3 * H + t] + tok * w_ih0[3 * H + t];
            const float i_ = sigmoidf_(gi);
            const float f_ = sigmoidf_(gf);
            const float g_ = tanhf(gg);
            const float o_ = sigmoidf_(go);
            const float cn = f_ * c0_reg + i_ * g_;
            c0_reg = cn;
            h0s[t] = o_ * tanhf(cn);
        }
        __syncthreads();

        // per wave: fused g1 row (w_ih1@h0) and next-step v0 row (w_hh0@h0)
        {
            const float* wA = w_ih1 + (size_t)rowR * H;
            const float* wB = w_hh0 + (size_t)rowR * H;
            float accA = 0.f, accB = 0.f;
            #pragma unroll
            for (int k = 0; k < 4; k++) {
                const int c = k * 256 + lane * 4;
                accA += dot4(*(const float4*)(wA + c), h0s, c);
                accB += dot4(*(const float4*)(wB + c), h0s, c);
            }
            accA = wave_reduce_sum(accA);
            accB = wave_reduce_sum(accB);
            if (lane == 0) {
                g1s[wave]  = accA + u1[rowR];
                v0o[rowR]  = accB + b_ih0[rowR] + b_hh0[rowR];
            }
        }
        __syncthreads();

        // cell1: this block's 4 elements; c1 lives in LDS
        if (t < 4) {
            const float i_ = sigmoidf_(g1s[t]);
            const float f_ = sigmoidf_(g1s[4 + t]);
            const float g_ = tanhf(g1s[8 + t]);
            const float o_ = sigmoidf_(g1s[12 + t]);
            const float cn = f_ * c1s[t] + i_ * g_;
            c1s[t] = cn;
            h1g[b * 4 + t] = o_ * tanhf(cn);
        }

        grid_sync(cnt, gen);

        // ================= phase B: fc + argmax + u1 =================
        float* out_row = out + (size_t)step * V;

        h1s[t] = h1g[t];
        if (t < 128) aprx[t] = -1.f;
        __syncthreads();

        unsigned long long bestKey = 0ull;

        if (use16) {
            // ---- pass 1: fp16 approx values, two rows fused for MLP ----
            #pragma unroll
            for (int i = 0; i < 8; i += 2) {
                const int rlA = i * 16 + wave;       // <= 111, always valid
                const int rlB = rlA + 16;
                const bool vB = (rlB < RPB);
                const int rowA = b * RPB + rlA;
                const int rowB = b * RPB + rlB;
                const __half* pA = wfc16 + (size_t)rowA * H;
                const __half* pB = wfc16 + (size_t)rowB * H;
                float aA = 0.f, aB = 0.f;
                #pragma unroll
                for (int k = 0; k < 2; k++) {
                    const int e = k * 512 + lane * 8;
                    const float4 hv0 = *(const float4*)(h1s + e);
                    const float4 hv1 = *(const float4*)(h1s + e + 4);
                    const float4 rA = *(const float4*)(pA + e);
                    const __half2* ha = (const __half2*)&rA;
                    float2 f0 = __half22float2(ha[0]), f1 = __half22float2(ha[1]);
                    float2 f2 = __half22float2(ha[2]), f3 = __half22float2(ha[3]);
                    aA += f0.x * hv0.x + f0.y * hv0.y + f1.x * hv0.z + f1.y * hv0.w
                        + f2.x * hv1.x + f2.y * hv1.y + f3.x * hv1.z + f3.y * hv1.w;
                    if (vB) {
                        const float4 rB = *(const float4*)(pB + e);
                        const __half2* hb = (const __half2*)&rB;
                        float2 g0 = __half22float2(hb[0]), g1 = __half22float2(hb[1]);
                        float2 g2 = __half22float2(hb[2]), g3 = __half22float2(hb[3]);
                        aB += g0.x * hv0.x + g0.y * hv0.y + g1.x * hv0.z + g1.y * hv0.w
                            + g2.x * hv1.x + g2.y * hv1.y + g3.x * hv1.z + g3.y * hv1.w;
                    }
                }
                aA = wave_reduce_sum(aA);
                aB = wave_reduce_sum(aB);
                if (lane == 0) {
                    float p = aA + b_fc[rowA];
                    p = p > 0.f ? p : 0.f;
                    __builtin_nontemporal_store(p, &out_row[rowA]);
                    aprx[rlA] = p;
                    if (vB) {
                        float q = aB + b_fc[rowB];
                        q = q > 0.f ? q : 0.f;
                        __builtin_nontemporal_store(q, &out_row[rowB]);
                        aprx[rlB] = q;
                    }
                }
            }
            __syncthreads();

            // ---- block approx max ----
            if (wave == 0) {
                float m = fmaxf(aprx[lane], aprx[lane + 64]);
                m = wave_reduce_max(m);
                if (lane == 0) Amax_s = m;
            }
            __syncthreads();
            const float thresh = Amax_s - 0.01f;   // fp16 dot error << 0.005

            // ---- pass 2: fp32 rescue of near-max rows (exact argmax) ----
            #pragma unroll
            for (int i = 0; i < 8; i++) {
                const int rl = i * 16 + wave;
                if (rl >= RPB) break;
                const float av = aprx[rl];          // wave-uniform
                if (av >= thresh) {
                    const int row = b * RPB + rl;
                    const float* wrow = w_fc + (size_t)row * H;
                    float acc = 0.f;
                    #pragma unroll
                    for (int k = 0; k < 4; k++) {
                        const int c = k * 256 + lane * 4;
                        acc += dot4(*(const float4*)(wrow + c), h1s, c);
                    }
                    acc = wave_reduce_sum(acc);
                    if (lane == 0) {
                        float p = acc + b_fc[row];
                        p = p > 0.f ? p : 0.f;
                        __builtin_nontemporal_store(p, &out_row[row]);  // exact
                        const unsigned long long key =
                            ((unsigned long long)__float_as_uint(p) << 32) |
                            (0xFFFFFFFFu - (unsigned int)row);
                        if (key > bestKey) bestKey = key;
                    }
                }
            }
        } else {
            // ---- fp32 fallback path ----
            #pragma unroll
            for (int i = 0; i < 8; i++) {
                const int rl = i * 16 + wave;
                if (rl >= RPB) break;
                const int row = b * RPB + rl;
                const float* wrow = w_fc + (size_t)row * H;
                float acc = 0.f;
                #pragma unroll
                for (int k = 0; k < 4; k++) {
                    const int c = k * 256 + lane * 4;
                    acc += dot4(*(const float4*)(wrow + c), h1s, c);
                }
                acc = wave_reduce_sum(acc);
                if (lane == 0) {
                    float p = acc + b_fc[row];
                    p = p > 0.f ? p : 0.f;
                    __builtin_nontemporal_store(p, &out_row[row]);
                    const unsigned long long key =
                        ((unsigned long long)__float_as_uint(p) << 32) |
                        (0xFFFFFFFFu - (unsigned int)row);
                    if (key > bestKey) bestKey = key;
                }
            }
        }

        // ---- next-step u1 row for this wave ----
        {
            const float* wrow = w_hh1 + (size_t)rowR * H;
            float acc = 0.f;
            #pragma unroll
            for (int k = 0; k < 4; k++) {
                const int c = k * 256 + lane * 4;
                acc += dot4(*(const float4*)(wrow + c), h1s, c);
            }
            acc = wave_reduce_sum(acc);
            if (lane == 0) u1[rowR] = acc + b_ih1[rowR] + b_hh1[rowR];
        }

        if (lane == 0) wkey[wave] = bestKey;
        __syncthreads();
        if (t == 0) {
            unsigned long long k = wkey[0];
            #pragma unroll
            for (int i = 1; i < 16; i++) k = (wkey[i] > k) ? wkey[i] : k;
            keys[b] = k;
        }

        grid_sync(cnt, gen);
    }
}

// ---------------------------------------------------------------------------
// Host launcher
// ---------------------------------------------------------------------------
extern "C" void kernel_launch(void* const* d_in, const int* in_sizes, int n_in,
                              void* d_out, int out_size, void* d_ws, size_t ws_size,
                              hipStream_t stream)
{
    const int*   y     = (const int*)  d_in[0];
    const float* ctx   = (const float*)d_in[1];
    const float* w_ih0 = (const float*)d_in[2];
    const float* w_hh0 = (const float*)d_in[3];
    const float* b_ih0 = (const float*)d_in[4];
    const float* b_hh0 = (const float*)d_in[5];
    const float* w_ih1 = (const float*)d_in[6];
    const float* w_hh1 = (const float*)d_in[7];
    const float* b_ih1 = (const float*)d_in[8];
    const float* b_hh1 = (const float*)d_in[9];
    const float* w_fc  = (const float*)d_in[10];
    const float* b_fc  = (const float*)d_in[11];
    float* out = (float*)d_out;

    const size_t FC16_BYTES  = (size_t)V * H * sizeof(__half);   // 65,536,000
    const size_t STATE_BYTES = 32768 + 16384 + 4096 + 2048 + 256;
    const int use16 = (ws_size >= FC16_BYTES + STATE_BYTES) ? 1 : 0;

    char* ws = (char*)d_ws;
    __half* wfc16 = (__half*)ws;
    char* base = ws + (use16 ? FC16_BYTES : 0);
    float* v0g = (float*)(base + 0);                                // [2][4096]
    float* u1  = (float*)(base + 32768);                            // [4096]
    float* h1g = (float*)(base + 49152);                            // [1024]
    unsigned long long* keys = (unsigned long long*)(base + 53248); // [256]
    unsigned int* bar = (unsigned int*)(base + 55296);              // [64] cnt@0, gen@128B

    // out row 0 is defined as zeros
    hipMemsetAsync(d_out, 0, (size_t)V * sizeof(float), stream);
    // barrier state must be zeroed every run (workspace may be poisoned)
    hipMemsetAsync(bar, 0, 256, stream);

    if (use16) {
        convert_fc<<<1024, 256, 0, stream>>>(w_fc, wfc16, V * H / 2);
    }

    persistent_kernel<<<NB, NT, 0, stream>>>(
        y, ctx, w_ih0, w_hh0, b_ih0, b_hh0,
        w_ih1, w_hh1, b_ih1, b_hh1,
        w_fc, wfc16, b_fc,
        v0g, u1, h1g, keys, bar, out, use16);
}

// Round 2
// 60113.959 us; speedup vs baseline: 1.8610x; 1.8610x over previous
//
#include <hip/hip_runtime.h>
#include <cstdint>
#include <cstddef>

#define H   1024
#define V   32000
#define L   2048
#define G4  4096      // 4*H
#define NB  256       // blocks
#define NT  1024      // threads per block (16 waves of 64)
#define RPB (V / NB)  // 125 FC rows per block

// final-GEMM config
#define GNB   500     // 32000 / 64 rows per block
#define GT    512     // threads (8 waves)
#define GS    8       // steps per chunk
#define GR    8       // rows per wave
#define NCHUNK (L / GS)  // 256

// ---------------------------------------------------------------------------
__device__ __forceinline__ float wave_reduce_sum(float v) {
    #pragma unroll
    for (int off = 32; off > 0; off >>= 1) v += __shfl_down(v, off);
    return v;
}

__device__ __forceinline__ float wave_reduce_max(float v) {
    #pragma unroll
    for (int off = 32; off > 0; off >>= 1) v = fmaxf(v, __shfl_down(v, off));
    return v;
}

__device__ __forceinline__ unsigned long long wave_reduce_max_u64(unsigned long long v) {
    #pragma unroll
    for (int off = 32; off > 0; off >>= 1) {
        const unsigned long long o = __shfl_down(v, off);
        v = (o > v) ? o : v;
    }
    return v;
}

__device__ __forceinline__ float sigmoidf_(float x) {
    return 1.0f / (1.0f + expf(-x));
}

__device__ __forceinline__ float dot4(const float4 w, const float* __restrict__ h, int c) {
    return w.x * h[c] + w.y * h[c + 1] + w.z * h[c + 2] + w.w * h[c + 3];
}

// sign-extend byte `pos` of dword w to float
__device__ __forceinline__ float sb2f(int w, int pos) {
    return (float)((w << ((3 - pos) * 8)) >> 24);
}

// ---------------------------------------------------------------------------
// One-time: w_fc fp32 -> per-row-scaled int8 + exact quant-error L2 norm.
// scl_eps[row] = {scale, ||w_row - scale*q_row||_2}; emax_bits = max eps2.
// ---------------------------------------------------------------------------
__global__ __launch_bounds__(256) void quant_fc(
    const float* __restrict__ src, signed char* __restrict__ dst,
    float2* __restrict__ scl_eps, unsigned int* __restrict__ emax_bits)
{
    const int gw   = (blockIdx.x * blockDim.x + threadIdx.x) >> 6;
    const int lane = threadIdx.x & 63;
    const int nw   = (gridDim.x * blockDim.x) >> 6;
    for (int row = gw; row < V; row += nw) {
        const float* p = src + (size_t)row * H + lane * 16;
        float w[16];
        #pragma unroll
        for (int j = 0; j < 4; j++) {
            const float4 f = *(const float4*)(p + j * 4);
            w[j * 4 + 0] = f.x; w[j * 4 + 1] = f.y;
            w[j * 4 + 2] = f.z; w[j * 4 + 3] = f.w;
        }
        float m = 0.f;
        #pragma unroll
        for (int j = 0; j < 16; j++) m = fmaxf(m, fabsf(w[j]));
        m = wave_reduce_max(m);
        m = __shfl(m, 0);
        const float scale = fmaxf(m, 1e-30f) / 127.f;
        const float inv   = 127.f / fmaxf(m, 1e-30f);
        int q[16];
        float esq = 0.f;
        #pragma unroll
        for (int j = 0; j < 16; j++) {
            q[j] = __float2int_rn(w[j] * inv);
            const float e = w[j] - scale * (float)q[j];
            esq += e * e;
        }
        esq = wave_reduce_sum(esq);
        const unsigned int d0 = (q[0] & 255) | ((q[1] & 255) << 8) | ((q[2] & 255) << 16) | ((unsigned int)(q[3] & 255) << 24);
        const unsigned int d1 = (q[4] & 255) | ((q[5] & 255) << 8) | ((q[6] & 255) << 16) | ((unsigned int)(q[7] & 255) << 24);
        const unsigned int d2 = (q[8] & 255) | ((q[9] & 255) << 8) | ((q[10] & 255) << 16) | ((unsigned int)(q[11] & 255) << 24);
        const unsigned int d3 = (q[12] & 255) | ((q[13] & 255) << 8) | ((q[14] & 255) << 16) | ((unsigned int)(q[15] & 255) << 24);
        *(int4*)(dst + (size_t)row * H + lane * 16) =
            make_int4((int)d0, (int)d1, (int)d2, (int)d3);
        if (lane == 0) {
            const float e2 = sqrtf(esq) + 1e-12f;
            scl_eps[row] = make_float2(scale, e2);
            atomicMax(emax_bits, __float_as_uint(e2));
        }
    }
}

// ---------------------------------------------------------------------------
// Init: v0 = w_hh0@h0_init + biases, u1 = w_hh1@h1_init + biases,
//       c0/c1/h1g from ctx, keys seeded with y[0].
// ---------------------------------------------------------------------------
__global__ __launch_bounds__(NT) void init_kernel(
    const int* __restrict__ y, const float* __restrict__ ctx,
    const float* __restrict__ w_hh0, const float* __restrict__ b_ih0,
    const float* __restrict__ b_hh0,
    const float* __restrict__ w_hh1, const float* __restrict__ b_ih1,
    const float* __restrict__ b_hh1,
    float* __restrict__ v0, float* __restrict__ u1,
    float* __restrict__ c0, float* __restrict__ c1,
    float* __restrict__ h1g, unsigned long long* __restrict__ keys)
{
    __shared__ __align__(16) float h0s[H];
    __shared__ __align__(16) float h1s[H];
    const int b = blockIdx.x, t = threadIdx.x;
    h0s[t] = ctx[t];
    h1s[t] = ctx[H + t];
    __syncthreads();

    const int wave = t >> 6, lane = t & 63;
    const int rowR = (wave >> 2) * H + b * 4 + (wave & 3);
    {
        const float* w0r = w_hh0 + (size_t)rowR * H;
        const float* w1r = w_hh1 + (size_t)rowR * H;
        float accV = 0.f, accU = 0.f;
        #pragma unroll
        for (int k = 0; k < 4; k++) {
            const int c = k * 256 + lane * 4;
            accV += dot4(*(const float4*)(w0r + c), h0s, c);
            accU += dot4(*(const float4*)(w1r + c), h1s, c);
        }
        accV = wave_reduce_sum(accV);
        accU = wave_reduce_sum(accU);
        if (lane == 0) {
            v0[rowR] = accV + b_ih0[rowR] + b_hh0[rowR];
            u1[rowR] = accU + b_ih1[rowR] + b_hh1[rowR];
        }
    }
    if (b == 0) {
        c0[t]  = ctx[t];
        c1[t]  = ctx[H + t];
        h1g[t] = ctx[H + t];
        if (t < NB) keys[t] = 0ull;
        if (t == 0) {
            keys[0] = ((unsigned long long)0x7F800000u << 32) |
                      (0xFFFFFFFFu - (unsigned int)y[0]);
        }
    }
}

// ---------------------------------------------------------------------------
// K_A: argmax finalize (redundant), cell0 (redundant), fused w_ih1@h0 /
//      w_hh0@h0 per wave, cell1 for this block's 4 h1 elems (+h1 history).
// ---------------------------------------------------------------------------
__global__ __launch_bounds__(NT) void lstm_kernel(
    const float* __restrict__ w_ih0, const float* __restrict__ w_ih1,
    const float* __restrict__ w_hh0,
    const float* __restrict__ b_ih0, const float* __restrict__ b_hh0,
    const float* __restrict__ v0_in, float* __restrict__ v0_out,
    const float* __restrict__ u1,
    const float* __restrict__ c0_in, float* __restrict__ c0_out,
    float* __restrict__ c1, float* __restrict__ h1g,
    const unsigned long long* __restrict__ keys,
    float* __restrict__ h1_hist, const int step)
{
    __shared__ __align__(16) float h0s[H];
    __shared__ float g1s[16];
    __shared__ unsigned long long kred[4];
    const int b = blockIdx.x, t = threadIdx.x;
    const int wave = t >> 6, lane = t & 63;

    // 1. argmax finalize over 256 block keys (redundant per block)
    if (wave < 4) {
        unsigned long long k = keys[t];           // t < 256
        k = wave_reduce_max_u64(k);
        if (lane == 0) kred[wave] = k;
    }
    __syncthreads();
    unsigned long long kk = kred[0];
    kk = (kred[1] > kk) ? kred[1] : kk;
    kk = (kred[2] > kk) ? kred[2] : kk;
    kk = (kred[3] > kk) ? kred[3] : kk;
    const float tok =
        (float)(unsigned int)(0xFFFFFFFFu - (unsigned int)(kk & 0xFFFFFFFFull));

    // 2. cell0 (block-redundant), element j = t
    {
        const float gi = v0_in[t]         + tok * w_ih0[t];
        const float gf = v0_in[H + t]     + tok * w_ih0[H + t];
        const float gg = v0_in[2 * H + t] + tok * w_ih0[2 * H + t];
        const float go = v0_in[3 * H + t] + tok * w_ih0[3 * H + t];
        const float i_ = sigmoidf_(gi);
        const float f_ = sigmoidf_(gf);
        const float g_ = tanhf(gg);
        const float o_ = sigmoidf_(go);
        const float cn = f_ * c0_in[t] + i_ * g_;
        if (b == 0) c0_out[t] = cn;
        h0s[t] = o_ * tanhf(cn);
    }
    __syncthreads();

    // 3. per wave: fused g1 row (w_ih1@h0) and next-step v0 row (w_hh0@h0)
    const int rowR = (wave >> 2) * H + b * 4 + (wave & 3);
    {
        const float* wA = w_ih1 + (size_t)rowR * H;
        const float* wB = w_hh0 + (size_t)rowR * H;
        float accA = 0.f, accB = 0.f;
        #pragma unroll
        for (int k = 0; k < 4; k++) {
            const int c = k * 256 + lane * 4;
            accA += dot4(*(const float4*)(wA + c), h0s, c);
            accB += dot4(*(const float4*)(wB + c), h0s, c);
        }
        accA = wave_reduce_sum(accA);
        accB = wave_reduce_sum(accB);
        if (lane == 0) {
            g1s[wave]    = accA + u1[rowR];
            v0_out[rowR] = accB + b_ih0[rowR] + b_hh0[rowR];
        }
    }
    __syncthreads();

    // 4. cell1: this block's 4 elements
    if (t < 4) {
        const float i_ = sigmoidf_(g1s[t]);
        const float f_ = sigmoidf_(g1s[4 + t]);
        const float g_ = tanhf(g1s[8 + t]);
        const float o_ = sigmoidf_(g1s[12 + t]);
        const float cn = f_ * c1[b * 4 + t] + i_ * g_;
        c1[b * 4 + t] = cn;
        const float hv = o_ * tanhf(cn);
        h1g[b * 4 + t] = hv;
        if (h1_hist) h1_hist[(size_t)step * H + b * 4 + t] = hv;
    }
}

// ---------------------------------------------------------------------------
// K_B (screen): int8 approx FC -> block max -> SOUND rescue window
// (Cauchy-Schwarz: |err| <= ||eps_row||_2 * ||h||_2) -> exact fp32 keys.
// No out writes (final GEMM produces all outputs exactly). Also next u1.
// ---------------------------------------------------------------------------
__global__ __launch_bounds__(NT) void screen_kernel(
    const signed char* __restrict__ wq8, const float2* __restrict__ scl_eps,
    const unsigned int* __restrict__ emax_bits,
    const float* __restrict__ w_fc, const float* __restrict__ b_fc,
    const float* __restrict__ w_hh1, const float* __restrict__ b_ih1,
    const float* __restrict__ b_hh1,
    const float* __restrict__ h1g, float* __restrict__ u1,
    unsigned long long* __restrict__ keys)
{
    __shared__ __align__(16) float h1s[H];
    __shared__ float aprx[128];
    __shared__ float red[16];
    __shared__ float Amax_s, Hl2_s;
    __shared__ unsigned long long wkey[16];
    const int b = blockIdx.x, t = threadIdx.x;
    const int wave = t >> 6, lane = t & 63;

    h1s[t] = h1g[t];
    if (t < 128) aprx[t] = -1.f;
    __syncthreads();

    // ||h||_2 partials
    {
        float sq = h1s[t] * h1s[t];
        sq = wave_reduce_sum(sq);
        if (lane == 0) red[wave] = sq;
    }

    // hoisted h slice (lane-contiguous 16 floats, matches int8 layout)
    const float4 hA = *(const float4*)(h1s + lane * 16);
    const float4 hB = *(const float4*)(h1s + lane * 16 + 4);
    const float4 hC = *(const float4*)(h1s + lane * 16 + 8);
    const float4 hD = *(const float4*)(h1s + lane * 16 + 12);

    // ---- pass 1: int8 approx values ----
    #pragma unroll
    for (int i = 0; i < 8; i++) {
        const int rl = i * 16 + wave;
        if (rl >= RPB) break;
        const int row = b * RPB + rl;
        const int4 qv = *(const int4*)(wq8 + (size_t)row * H + lane * 16);
        float acc;
        acc  = sb2f(qv.x, 0) * hA.x + sb2f(qv.x, 1) * hA.y + sb2f(qv.x, 2) * hA.z + sb2f(qv.x, 3) * hA.w;
        acc += sb2f(qv.y, 0) * hB.x + sb2f(qv.y, 1) * hB.y + sb2f(qv.y, 2) * hB.z + sb2f(qv.y, 3) * hB.w;
        acc += sb2f(qv.z, 0) * hC.x + sb2f(qv.z, 1) * hC.y + sb2f(qv.z, 2) * hC.z + sb2f(qv.z, 3) * hC.w;
        acc += sb2f(qv.w, 0) * hD.x + sb2f(qv.w, 1) * hD.y + sb2f(qv.w, 2) * hD.z + sb2f(qv.w, 3) * hD.w;
        acc = wave_reduce_sum(acc);
        if (lane == 0) {
            float p = scl_eps[row].x * acc + b_fc[row];
            p = p > 0.f ? p : 0.f;
            aprx[rl] = p;
        }
    }
    __syncthreads();

    // ---- block approx max + ||h||_2 finalize ----
    if (t == 0) {
        float s = 0.f;
        #pragma unroll
        for (int i = 0; i < 16; i++) s += red[i];
        Hl2_s = sqrtf(s);
    }
    if (wave == 0) {
        float m = fmaxf(aprx[lane], aprx[lane + 64]);
        m = wave_reduce_max(m);
        if (lane == 0) Amax_s = m;
    }
    __syncthreads();

    // sound window: both the candidate's and the approx-max row's error are
    // bounded by emax * ||h||_2 (Cauchy-Schwarz, exact eps norms from quant).
    const float emax   = __uint_as_float(*emax_bits);
    const float thresh = Amax_s - (2.f * emax * Hl2_s + 1e-3f);

    unsigned long long bestKey = 0ull;

    // ---- pass 2: fp32 rescue (exact argmax keys) ----
    #pragma unroll
    for (int i = 0; i < 8; i++) {
        const int rl = i * 16 + wave;
        if (rl >= RPB) break;
        const float av = aprx[rl];          // wave-uniform
        if (av >= thresh) {
            const int row = b * RPB + rl;
            const float* wrow = w_fc + (size_t)row * H;
            float acc = 0.f;
            #pragma unroll
            for (int k = 0; k < 4; k++) {
                const int c = k * 256 + lane * 4;
                acc += dot4(*(const float4*)(wrow + c), h1s, c);
            }
            acc = wave_reduce_sum(acc);
            if (lane == 0) {
                float p = acc + b_fc[row];
                p = p > 0.f ? p : 0.f;
                const unsigned long long key =
                    ((unsigned long long)__float_as_uint(p) << 32) |
                    (0xFFFFFFFFu - (unsigned int)row);
                if (key > bestKey) bestKey = key;
            }
        }
    }

    // ---- next-step u1 row for this wave ----
    {
        const int rowR = (wave >> 2) * H + b * 4 + (wave & 3);
        const float* wrow = w_hh1 + (size_t)rowR * H;
        float acc = 0.f;
        #pragma unroll
        for (int k = 0; k < 4; k++) {
            const int c = k * 256 + lane * 4;
            acc += dot4(*(const float4*)(wrow + c), h1s, c);
        }
        acc = wave_reduce_sum(acc);
        if (lane == 0) u1[rowR] = acc + b_ih1[rowR] + b_hh1[rowR];
    }

    if (lane == 0) wkey[wave] = bestKey;
    __syncthreads();
    if (t == 0) {
        unsigned long long k = wkey[0];
        #pragma unroll
        for (int i = 1; i < 16; i++) k = (wkey[i] > k) ? wkey[i] : k;
        keys[b] = k;
    }
}

// ---------------------------------------------------------------------------
// Fallback K_B (workspace too small): full fp32 FC with out writes + keys.
// ---------------------------------------------------------------------------
__global__ __launch_bounds__(NT) void fc32_kernel(
    const float* __restrict__ w_fc, const float* __restrict__ b_fc,
    const float* __restrict__ w_hh1, const float* __restrict__ b_ih1,
    const float* __restrict__ b_hh1,
    const float* __restrict__ h1g, float* __restrict__ u1,
    unsigned long long* __restrict__ keys, float* __restrict__ out_row)
{
    __shared__ __align__(16) float h1s[H];
    __shared__ unsigned long long wkey[16];
    const int b = blockIdx.x, t = threadIdx.x;
    const int wave = t >> 6, lane = t & 63;

    h1s[t] = h1g[t];
    __syncthreads();

    unsigned long long bestKey = 0ull;
    #pragma unroll
    for (int i = 0; i < 8; i++) {
        const int rl = i * 16 + wave;
        if (rl >= RPB) break;
        const int row = b * RPB + rl;
        const float* wrow = w_fc + (size_t)row * H;
        float acc = 0.f;
        #pragma unroll
        for (int k = 0; k < 4; k++) {
            const int c = k * 256 + lane * 4;
            acc += dot4(*(const float4*)(wrow + c), h1s, c);
        }
        acc = wave_reduce_sum(acc);
        if (lane == 0) {
            float p = acc + b_fc[row];
            p = p > 0.f ? p : 0.f;
            out_row[row] = p;
            const unsigned long long key =
                ((unsigned long long)__float_as_uint(p) << 32) |
                (0xFFFFFFFFu - (unsigned int)row);
            if (key > bestKey) bestKey = key;
        }
    }

    {
        const int rowR = (wave >> 2) * H + b * 4 + (wave & 3);
        const float* wrow = w_hh1 + (size_t)rowR * H;
        float acc = 0.f;
        #pragma unroll
        for (int k = 0; k < 4; k++) {
            const int c = k * 256 + lane * 4;
            acc += dot4(*(const float4*)(wrow + c), h1s, c);
        }
        acc = wave_reduce_sum(acc);
        if (lane == 0) u1[rowR] = acc + b_ih1[rowR] + b_hh1[rowR];
    }

    if (lane == 0) wkey[wave] = bestKey;
    __syncthreads();
    if (t == 0) {
        unsigned long long k = wkey[0];
        #pragma unroll
        for (int i = 1; i < 16; i++) k = (wkey[i] > k) ? wkey[i] : k;
        keys[b] = k;
    }
}

// ---------------------------------------------------------------------------
// Final batched exact FC: out[t] = relu(W_fc @ h1_hist[t] + b), t = 1..L-1.
// W slice (64 rows/block) held in registers; h chunks staged in LDS.
// ---------------------------------------------------------------------------
__global__ __launch_bounds__(GT) void out_gemm(
    const float* __restrict__ w_fc, const float* __restrict__ b_fc,
    const float* __restrict__ h1_hist, float* __restrict__ out)
{
    __shared__ __align__(16) float hs[GS][H];       // 32 KB
    __shared__ float stage[GS][64];                 // 2 KB
    const int b = blockIdx.x, t = threadIdx.x;
    const int wave = t >> 6, lane = t & 63;
    const int row0 = b * 64 + wave * GR;

    // W rows for this wave, persistent in registers (dot4 pattern)
    float4 wr[GR][4];
    #pragma unroll
    for (int r = 0; r < GR; r++)
        #pragma unroll
        for (int k = 0; k < 4; k++)
            wr[r][k] = *(const float4*)(w_fc + (size_t)(row0 + r) * H + k * 256 + lane * 4);

    for (int chunk = 0; chunk < NCHUNK; ++chunk) {
        __syncthreads();
        {
            const float4* src = (const float4*)(h1_hist + (size_t)chunk * GS * H);
            float4* dsts = (float4*)(&hs[0][0]);
            #pragma unroll
            for (int j = 0; j < 4; j++) dsts[j * GT + t] = src[j * GT + t];
        }
        __syncthreads();

        #pragma unroll
        for (int sb = 0; sb < 2; sb++) {
            float acc[GR][4];
            #pragma unroll
            for (int r = 0; r < GR; r++)
                #pragma unroll
                for (int s = 0; s < 4; s++) acc[r][s] = 0.f;
            #pragma unroll
            for (int k = 0; k < 4; k++) {
                const int c = k * 256 + lane * 4;
                const float4 h0 = *(const float4*)(&hs[sb * 4 + 0][c]);
                const float4 h1 = *(const float4*)(&hs[sb * 4 + 1][c]);
                const float4 h2 = *(const float4*)(&hs[sb * 4 + 2][c]);
                const float4 h3 = *(const float4*)(&hs[sb * 4 + 3][c]);
                #pragma unroll
                for (int r = 0; r < GR; r++) {
                    const float4 w = wr[r][k];
                    acc[r][0] += w.x * h0.x + w.y * h0.y + w.z * h0.z + w.w * h0.w;
                    acc[r][1] += w.x * h1.x + w.y * h1.y + w.z * h1.z + w.w * h1.w;
                    acc[r][2] += w.x * h2.x + w.y * h2.y + w.z * h2.z + w.w * h2.w;
                    acc[r][3] += w.x * h3.x + w.y * h3.y + w.z * h3.z + w.w * h3.w;
                }
            }
            #pragma unroll
            for (int r = 0; r < GR; r++)
                #pragma unroll
                for (int s = 0; s < 4; s++) {
                    const float vv = wave_reduce_sum(acc[r][s]);
                    if (lane == 0) stage[sb * 4 + s][wave * GR + r] = vv;
                }
        }
        __syncthreads();
        {
            const int s = t >> 6;              // 0..7
            const int col = t & 63;
            const int sidx = chunk * GS + s;
            if (sidx >= 1) {
                const float vv = stage[s][col] + b_fc[b * 64 + col];
                out[(size_t)sidx * V + b * 64 + col] = fmaxf(vv, 0.f);
            }
        }
    }
}

// ---------------------------------------------------------------------------
// Host launcher
// ---------------------------------------------------------------------------
extern "C" void kernel_launch(void* const* d_in, const int* in_sizes, int n_in,
                              void* d_out, int out_size, void* d_ws, size_t ws_size,
                              hipStream_t stream)
{
    const int*   y     = (const int*)  d_in[0];
    const float* ctx   = (const float*)d_in[1];
    const float* w_ih0 = (const float*)d_in[2];
    const float* w_hh0 = (const float*)d_in[3];
    const float* b_ih0 = (const float*)d_in[4];
    const float* b_hh0 = (const float*)d_in[5];
    const float* w_ih1 = (const float*)d_in[6];
    const float* w_hh1 = (const float*)d_in[7];
    const float* b_ih1 = (const float*)d_in[8];
    const float* b_hh1 = (const float*)d_in[9];
    const float* w_fc  = (const float*)d_in[10];
    const float* b_fc  = (const float*)d_in[11];
    float* out = (float*)d_out;

    const size_t WQ8_BYTES  = (size_t)V * H;              // 32,768,000
    const size_t SCL_BYTES  = (size_t)V * sizeof(float2); // 256,000
    const size_t HIST_BYTES = (size_t)L * H * sizeof(float); // 8,388,608
    const size_t STATE_BYTES = 67600;
    const int use8 = (ws_size >= WQ8_BYTES + SCL_BYTES + HIST_BYTES + STATE_BYTES) ? 1 : 0;

    char* ws = (char*)d_ws;
    signed char* wq8     = (signed char*)ws;
    float2*      scl_eps = (float2*)(ws + WQ8_BYTES);
    float*       h1_hist = (float*)(ws + WQ8_BYTES + SCL_BYTES);
    char* base = ws + (use8 ? (WQ8_BYTES + SCL_BYTES + HIST_BYTES) : 0);
    float* v0g = (float*)(base + 0);                                // [2][4096]
    float* u1  = (float*)(base + 32768);                            // [4096]
    float* c0  = (float*)(base + 49152);                            // [2][1024]
    float* c1  = (float*)(base + 57344);                            // [1024]
    float* h1g = (float*)(base + 61440);                            // [1024]
    unsigned long long* keys = (unsigned long long*)(base + 65536); // [256]
    unsigned int* emax_bits  = (unsigned int*)(base + 67584);       // [2]

    // out row 0 is defined as zeros
    hipMemsetAsync(d_out, 0, (size_t)V * sizeof(float), stream);

    if (use8) {
        hipMemsetAsync(emax_bits, 0, 8, stream);
        hipMemsetAsync(h1_hist, 0, (size_t)H * sizeof(float), stream);
        quant_fc<<<512, 256, 0, stream>>>(w_fc, wq8, scl_eps, emax_bits);
    }

    init_kernel<<<NB, NT, 0, stream>>>(y, ctx, w_hh0, b_ih0, b_hh0,
                                       w_hh1, b_ih1, b_hh1,
                                       v0g, u1, c0, c1, h1g, keys);

    for (int t = 1; t < L; t++) {
        const float* v0i = v0g + ((t - 1) & 1) * G4;
        float*       v0o = v0g + (t & 1) * G4;
        const float* c0i = c0 + ((t - 1) & 1) * H;
        float*       c0o = c0 + (t & 1) * H;
        lstm_kernel<<<NB, NT, 0, stream>>>(w_ih0, w_ih1, w_hh0, b_ih0, b_hh0,
                                           v0i, v0o, u1, c0i, c0o, c1, h1g, keys,
                                           use8 ? h1_hist : (float*)nullptr, t);
        if (use8) {
            screen_kernel<<<NB, NT, 0, stream>>>(wq8, scl_eps, emax_bits,
                                                 w_fc, b_fc,
                                                 w_hh1, b_ih1, b_hh1,
                                                 h1g, u1, keys);
        } else {
            fc32_kernel<<<NB, NT, 0, stream>>>(w_fc, b_fc,
                                               w_hh1, b_ih1, b_hh1,
                                               h1g, u1, keys,
                                               out + (size_t)t * V);
        }
    }

    if (use8) {
        out_gemm<<<GNB, GT, 0, stream>>>(w_fc, b_fc, h1_hist, out);
    }
}

// Round 3
// 53543.994 us; speedup vs baseline: 2.0893x; 1.1227x over previous
//
#include <hip/hip_runtime.h>
#include <cstdint>
#include <cstddef>

#define H   1024
#define V   32000
#define L   2048
#define G4  4096      // 4*H
#define NB  256       // blocks
#define NT  1024      // threads per block (16 waves of 64)
#define RPB (V / NB)  // 125 FC rows per block

// final-GEMM config
#define GNB   500     // 32000 / 64 rows per block
#define GT    512     // threads (8 waves)
#define GS    8       // steps per chunk
#define GR    8       // rows per wave
#define NCHUNK (L / GS)  // 256

// ---------------------------------------------------------------------------
__device__ __forceinline__ float wave_reduce_sum(float v) {
    #pragma unroll
    for (int off = 32; off > 0; off >>= 1) v += __shfl_down(v, off);
    return v;
}

__device__ __forceinline__ float wave_reduce_max(float v) {
    #pragma unroll
    for (int off = 32; off > 0; off >>= 1) v = fmaxf(v, __shfl_down(v, off));
    return v;
}

__device__ __forceinline__ unsigned long long wave_reduce_max_u64(unsigned long long v) {
    #pragma unroll
    for (int off = 32; off > 0; off >>= 1) {
        const unsigned long long o = __shfl_down(v, off);
        v = (o > v) ? o : v;
    }
    return v;
}

__device__ __forceinline__ float sigmoidf_(float x) {
    return 1.0f / (1.0f + expf(-x));
}

__device__ __forceinline__ float dot4(const float4 w, const float* __restrict__ h, int c) {
    return w.x * h[c] + w.y * h[c + 1] + w.z * h[c + 2] + w.w * h[c + 3];
}

// sign-extend byte `pos` of dword w to float
__device__ __forceinline__ float sb2f(int w, int pos) {
    return (float)((w << ((3 - pos) * 8)) >> 24);
}

// ---------------------------------------------------------------------------
// One-time: w_fc fp32 -> per-row-scaled int8 + exact quant-error L2 norm.
// scl_eps[row] = {scale, ||w_row - scale*q_row||_2}.
// ---------------------------------------------------------------------------
__global__ __launch_bounds__(256) void quant_fc(
    const float* __restrict__ src, signed char* __restrict__ dst,
    float2* __restrict__ scl_eps)
{
    const int gw   = (blockIdx.x * blockDim.x + threadIdx.x) >> 6;
    const int lane = threadIdx.x & 63;
    const int nw   = (gridDim.x * blockDim.x) >> 6;
    for (int row = gw; row < V; row += nw) {
        const float* p = src + (size_t)row * H + lane * 16;
        float w[16];
        #pragma unroll
        for (int j = 0; j < 4; j++) {
            const float4 f = *(const float4*)(p + j * 4);
            w[j * 4 + 0] = f.x; w[j * 4 + 1] = f.y;
            w[j * 4 + 2] = f.z; w[j * 4 + 3] = f.w;
        }
        float m = 0.f;
        #pragma unroll
        for (int j = 0; j < 16; j++) m = fmaxf(m, fabsf(w[j]));
        m = wave_reduce_max(m);
        m = __shfl(m, 0);
        const float scale = fmaxf(m, 1e-30f) / 127.f;
        const float inv   = 127.f / fmaxf(m, 1e-30f);
        int q[16];
        float esq = 0.f;
        #pragma unroll
        for (int j = 0; j < 16; j++) {
            q[j] = __float2int_rn(w[j] * inv);
            const float e = w[j] - scale * (float)q[j];
            esq += e * e;
        }
        esq = wave_reduce_sum(esq);
        const unsigned int d0 = (q[0] & 255) | ((q[1] & 255) << 8) | ((q[2] & 255) << 16) | ((unsigned int)(q[3] & 255) << 24);
        const unsigned int d1 = (q[4] & 255) | ((q[5] & 255) << 8) | ((q[6] & 255) << 16) | ((unsigned int)(q[7] & 255) << 24);
        const unsigned int d2 = (q[8] & 255) | ((q[9] & 255) << 8) | ((q[10] & 255) << 16) | ((unsigned int)(q[11] & 255) << 24);
        const unsigned int d3 = (q[12] & 255) | ((q[13] & 255) << 8) | ((q[14] & 255) << 16) | ((unsigned int)(q[15] & 255) << 24);
        *(int4*)(dst + (size_t)row * H + lane * 16) =
            make_int4((int)d0, (int)d1, (int)d2, (int)d3);
        if (lane == 0) {
            scl_eps[row] = make_float2(scale, sqrtf(esq) + 1e-12f);
        }
    }
}

// ---------------------------------------------------------------------------
// Init: v0 = w_hh0@h0_init + biases; c0/c1/h1g(buf0) from ctx; keys <- y[0].
// (u1 is now computed in-register inside lstm_kernel.)
// ---------------------------------------------------------------------------
__global__ __launch_bounds__(NT) void init_kernel(
    const int* __restrict__ y, const float* __restrict__ ctx,
    const float* __restrict__ w_hh0, const float* __restrict__ b_ih0,
    const float* __restrict__ b_hh0,
    float* __restrict__ v0, float* __restrict__ c0, float* __restrict__ c1,
    float* __restrict__ h1g0, unsigned long long* __restrict__ keys)
{
    __shared__ __align__(16) float h0s[H];
    const int b = blockIdx.x, t = threadIdx.x;
    h0s[t] = ctx[t];
    __syncthreads();

    const int wave = t >> 6, lane = t & 63;
    const int rowR = (wave >> 2) * H + b * 4 + (wave & 3);
    {
        const float* w0r = w_hh0 + (size_t)rowR * H;
        float accV = 0.f;
        #pragma unroll
        for (int k = 0; k < 4; k++) {
            const int c = k * 256 + lane * 4;
            accV += dot4(*(const float4*)(w0r + c), h0s, c);
        }
        accV = wave_reduce_sum(accV);
        if (lane == 0) v0[rowR] = accV + b_ih0[rowR] + b_hh0[rowR];
    }
    if (b == 0) {
        c0[t]   = ctx[t];
        c1[t]   = ctx[H + t];
        h1g0[t] = ctx[H + t];
        if (t < NB) keys[t] = 0ull;
        if (t == 0) {
            keys[0] = ((unsigned long long)0x7F800000u << 32) |
                      (0xFFFFFFFFu - (unsigned int)y[0]);
        }
    }
}

// ---------------------------------------------------------------------------
// K_A: argmax finalize (block-redundant), cell0 (block-redundant),
//      u1 row (w_hh1@h1_prev) computed in-register (loads issued at kernel
//      start, hidden under the serial prefix), fused w_ih1@h0 / w_hh0@h0,
//      cell1 for this block's 4 h1 elems (+h1 history).
// ---------------------------------------------------------------------------
__global__ __launch_bounds__(NT) void lstm_kernel(
    const float* __restrict__ w_ih0, const float* __restrict__ w_ih1,
    const float* __restrict__ w_hh0, const float* __restrict__ w_hh1,
    const float* __restrict__ b_ih0, const float* __restrict__ b_hh0,
    const float* __restrict__ b_ih1, const float* __restrict__ b_hh1,
    const float* __restrict__ v0_in, float* __restrict__ v0_out,
    const float* __restrict__ c0_in, float* __restrict__ c0_out,
    float* __restrict__ c1,
    const float* __restrict__ h1prev, float* __restrict__ h1out,
    const unsigned long long* __restrict__ keys,
    float* __restrict__ h1_hist, const int step)
{
    __shared__ __align__(16) float h0s[H];
    __shared__ __align__(16) float h1ps[H];
    __shared__ float g1s[16];
    __shared__ unsigned long long kred[4];
    const int b = blockIdx.x, t = threadIdx.x;
    const int wave = t >> 6, lane = t & 63;
    const int rowR = (wave >> 2) * H + b * 4 + (wave & 3);

    // --- issue the w_hh1 row loads immediately (they hide under the prefix)
    const float* wU = w_hh1 + (size_t)rowR * H;
    float4 wu[4];
    #pragma unroll
    for (int k = 0; k < 4; k++)
        wu[k] = *(const float4*)(wU + k * 256 + lane * 4);

    h1ps[t] = h1prev[t];

    // --- argmax finalize over 256 block keys (block-redundant)
    if (wave < 4) {
        unsigned long long k = keys[t];           // t < 256
        k = wave_reduce_max_u64(k);
        if (lane == 0) kred[wave] = k;
    }

    // --- cell0 operand loads (independent; issue before the barrier)
    const float v0a = v0_in[t],         v0b = v0_in[H + t];
    const float v0c = v0_in[2 * H + t], v0d = v0_in[3 * H + t];
    const float wia = w_ih0[t],         wib = w_ih0[H + t];
    const float wic = w_ih0[2 * H + t], wid = w_ih0[3 * H + t];
    const float c0v = c0_in[t];

    __syncthreads();   // kred + h1ps visible

    unsigned long long kk = kred[0];
    kk = (kred[1] > kk) ? kred[1] : kk;
    kk = (kred[2] > kk) ? kred[2] : kk;
    kk = (kred[3] > kk) ? kred[3] : kk;
    const float tok =
        (float)(unsigned int)(0xFFFFFFFFu - (unsigned int)(kk & 0xFFFFFFFFull));

    // --- u1 partial for this wave's row (from LDS h1_prev)
    float accU = 0.f;
    #pragma unroll
    for (int k = 0; k < 4; k++) {
        const int c = k * 256 + lane * 4;
        accU += dot4(wu[k], h1ps, c);
    }

    // --- cell0 (block-redundant), element j = t; c0 via global dbuf
    {
        const float gi = v0a + tok * wia;
        const float gf = v0b + tok * wib;
        const float gg = v0c + tok * wic;
        const float go = v0d + tok * wid;
        const float i_ = sigmoidf_(gi);
        const float f_ = sigmoidf_(gf);
        const float g_ = tanhf(gg);
        const float o_ = sigmoidf_(go);
        const float cn = f_ * c0v + i_ * g_;
        if (b == 0) c0_out[t] = cn;
        h0s[t] = o_ * tanhf(cn);
    }
    __syncthreads();

    // --- per wave: g1 row (w_ih1@h0 + accU) and next-step v0 row (w_hh0@h0)
    {
        const float* wA = w_ih1 + (size_t)rowR * H;
        const float* wB = w_hh0 + (size_t)rowR * H;
        float accA = 0.f, accB = 0.f;
        #pragma unroll
        for (int k = 0; k < 4; k++) {
            const int c = k * 256 + lane * 4;
            accA += dot4(*(const float4*)(wA + c), h0s, c);
            accB += dot4(*(const float4*)(wB + c), h0s, c);
        }
        const float g  = wave_reduce_sum(accA + accU);
        const float vv = wave_reduce_sum(accB);
        if (lane == 0) {
            g1s[wave]    = g  + b_ih1[rowR] + b_hh1[rowR];
            v0_out[rowR] = vv + b_ih0[rowR] + b_hh0[rowR];
        }
    }
    __syncthreads();

    // --- cell1: this block's 4 elements
    if (t < 4) {
        const float i_ = sigmoidf_(g1s[t]);
        const float f_ = sigmoidf_(g1s[4 + t]);
        const float g_ = tanhf(g1s[8 + t]);
        const float o_ = sigmoidf_(g1s[12 + t]);
        const float cn = f_ * c1[b * 4 + t] + i_ * g_;
        c1[b * 4 + t] = cn;
        const float hv = o_ * tanhf(cn);
        h1out[b * 4 + t] = hv;
        if (h1_hist) h1_hist[(size_t)step * H + b * 4 + t] = hv;
    }
}

// ---------------------------------------------------------------------------
// K_B (screen): int8 approx FC with depth-8 prefetch -> per-row sound bounds
// (Cauchy-Schwarz, per-row eps) -> fp32 rescue of candidates -> exact keys.
// No out writes (final GEMM produces all outputs exactly). No u1.
// ---------------------------------------------------------------------------
__global__ __launch_bounds__(NT) void screen_kernel(
    const signed char* __restrict__ wq8, const float2* __restrict__ scl_eps,
    const float* __restrict__ w_fc, const float* __restrict__ b_fc,
    const float* __restrict__ h1cur, unsigned long long* __restrict__ keys)
{
    __shared__ __align__(16) float h1s[H];
    __shared__ float lb[128], ub[128];
    __shared__ float red[16];
    __shared__ float LBmax_s;
    __shared__ unsigned long long wkey[16];
    const int b = blockIdx.x, t = threadIdx.x;
    const int wave = t >> 6, lane = t & 63;

    const float hv = h1cur[t];
    h1s[t] = hv;
    if (t < 128) { lb[t] = -3e38f; ub[t] = -3e38f; }
    {
        const float sq = wave_reduce_sum(hv * hv);
        if (lane == 0) red[wave] = sq;
    }
    __syncthreads();

    float Hl2;
    {
        float s = 0.f;
        #pragma unroll
        for (int i = 0; i < 16; i++) s += red[i];
        Hl2 = sqrtf(s);
    }

    // hoisted h slice (lane-contiguous 16 floats, matches int8 layout)
    const float4 hA = *(const float4*)(h1s + lane * 16);
    const float4 hB = *(const float4*)(h1s + lane * 16 + 4);
    const float4 hC = *(const float4*)(h1s + lane * 16 + 8);
    const float4 hD = *(const float4*)(h1s + lane * 16 + 12);

    // ---- pass 1: prefetch all 8 rows (8 loads in flight), then decode ----
    int4 qv[8];
    #pragma unroll
    for (int i = 0; i < 8; i++) {
        const int rl = i * 16 + wave;
        const int row = b * RPB + (rl < RPB ? rl : 0);
        qv[i] = *(const int4*)(wq8 + (size_t)row * H + lane * 16);
    }
    float acc[8];
    #pragma unroll
    for (int i = 0; i < 8; i++) {
        const int4 q = qv[i];
        float a;
        a  = sb2f(q.x, 0) * hA.x + sb2f(q.x, 1) * hA.y + sb2f(q.x, 2) * hA.z + sb2f(q.x, 3) * hA.w;
        a += sb2f(q.y, 0) * hB.x + sb2f(q.y, 1) * hB.y + sb2f(q.y, 2) * hB.z + sb2f(q.y, 3) * hB.w;
        a += sb2f(q.z, 0) * hC.x + sb2f(q.z, 1) * hC.y + sb2f(q.z, 2) * hC.z + sb2f(q.z, 3) * hC.w;
        a += sb2f(q.w, 0) * hD.x + sb2f(q.w, 1) * hD.y + sb2f(q.w, 2) * hD.z + sb2f(q.w, 3) * hD.w;
        acc[i] = a;
    }
    // 8 interleaved reduce trees (independent shuffle chains pipeline)
    #pragma unroll
    for (int off = 32; off > 0; off >>= 1) {
        #pragma unroll
        for (int i = 0; i < 8; i++) acc[i] += __shfl_down(acc[i], off);
    }
    if (lane == 0) {
        #pragma unroll
        for (int i = 0; i < 8; i++) {
            const int rl = i * 16 + wave;
            if (rl < RPB) {
                const int row = b * RPB + rl;
                const float2 se = scl_eps[row];
                float p = se.x * acc[i] + b_fc[row];
                p = fmaxf(p, 0.f);
                const float e = se.y * Hl2;   // sound per-row bound (relu 1-Lipschitz)
                ub[rl] = p + e;
                lb[rl] = p - e;
            }
        }
    }
    __syncthreads();

    // ---- block max of lower bounds ----
    if (wave == 0) {
        float m = fmaxf(lb[lane], lb[lane + 64]);
        m = wave_reduce_max(m);
        if (lane == 0) LBmax_s = m;
    }
    __syncthreads();
    const float LBmax = LBmax_s;

    unsigned long long bestKey = 0ull;

    // ---- pass 2: fp32 rescue of candidates (exact argmax keys) ----
    #pragma unroll
    for (int i = 0; i < 8; i++) {
        const int rl = i * 16 + wave;
        if (rl >= RPB) break;
        if (ub[rl] >= LBmax) {          // wave-uniform
            const int row = b * RPB + rl;
            const float* wrow = w_fc + (size_t)row * H;
            float a = 0.f;
            #pragma unroll
            for (int k = 0; k < 4; k++) {
                const int c = k * 256 + lane * 4;
                a += dot4(*(const float4*)(wrow + c), h1s, c);
            }
            a = wave_reduce_sum(a);
            if (lane == 0) {
                float p = a + b_fc[row];
                p = p > 0.f ? p : 0.f;
                const unsigned long long key =
                    ((unsigned long long)__float_as_uint(p) << 32) |
                    (0xFFFFFFFFu - (unsigned int)row);
                if (key > bestKey) bestKey = key;
            }
        }
    }

    if (lane == 0) wkey[wave] = bestKey;
    __syncthreads();
    if (t == 0) {
        unsigned long long k = wkey[0];
        #pragma unroll
        for (int i = 1; i < 16; i++) k = (wkey[i] > k) ? wkey[i] : k;
        keys[b] = k;
    }
}

// ---------------------------------------------------------------------------
// Fallback K_B (workspace too small): full fp32 FC with out writes + keys.
// ---------------------------------------------------------------------------
__global__ __launch_bounds__(NT) void fc32_kernel(
    const float* __restrict__ w_fc, const float* __restrict__ b_fc,
    const float* __restrict__ h1cur, unsigned long long* __restrict__ keys,
    float* __restrict__ out_row)
{
    __shared__ __align__(16) float h1s[H];
    __shared__ unsigned long long wkey[16];
    const int b = blockIdx.x, t = threadIdx.x;
    const int wave = t >> 6, lane = t & 63;

    h1s[t] = h1cur[t];
    __syncthreads();

    unsigned long long bestKey = 0ull;
    #pragma unroll
    for (int i = 0; i < 8; i++) {
        const int rl = i * 16 + wave;
        if (rl >= RPB) break;
        const int row = b * RPB + rl;
        const float* wrow = w_fc + (size_t)row * H;
        float a = 0.f;
        #pragma unroll
        for (int k = 0; k < 4; k++) {
            const int c = k * 256 + lane * 4;
            a += dot4(*(const float4*)(wrow + c), h1s, c);
        }
        a = wave_reduce_sum(a);
        if (lane == 0) {
            float p = a + b_fc[row];
            p = p > 0.f ? p : 0.f;
            out_row[row] = p;
            const unsigned long long key =
                ((unsigned long long)__float_as_uint(p) << 32) |
                (0xFFFFFFFFu - (unsigned int)row);
            if (key > bestKey) bestKey = key;
        }
    }

    if (lane == 0) wkey[wave] = bestKey;
    __syncthreads();
    if (t == 0) {
        unsigned long long k = wkey[0];
        #pragma unroll
        for (int i = 1; i < 16; i++) k = (wkey[i] > k) ? wkey[i] : k;
        keys[b] = k;
    }
}

// ---------------------------------------------------------------------------
// Final batched exact FC: out[t] = relu(W_fc @ h1_hist[t] + b), t = 1..L-1.
// W slice (64 rows/block) held in registers; h chunks staged in LDS.
// ---------------------------------------------------------------------------
__global__ __launch_bounds__(GT) void out_gemm(
    const float* __restrict__ w_fc, const float* __restrict__ b_fc,
    const float* __restrict__ h1_hist, float* __restrict__ out)
{
    __shared__ __align__(16) float hs[GS][H];       // 32 KB
    __shared__ float stage[GS][64];                 // 2 KB
    const int b = blockIdx.x, t = threadIdx.x;
    const int wave = t >> 6, lane = t & 63;
    const int row0 = b * 64 + wave * GR;

    // W rows for this wave, persistent in registers (dot4 pattern)
    float4 wr[GR][4];
    #pragma unroll
    for (int r = 0; r < GR; r++)
        #pragma unroll
        for (int k = 0; k < 4; k++)
            wr[r][k] = *(const float4*)(w_fc + (size_t)(row0 + r) * H + k * 256 + lane * 4);

    for (int chunk = 0; chunk < NCHUNK; ++chunk) {
        __syncthreads();
        {
            const float4* src = (const float4*)(h1_hist + (size_t)chunk * GS * H);
            float4* dsts = (float4*)(&hs[0][0]);
            #pragma unroll
            for (int j = 0; j < 4; j++) dsts[j * GT + t] = src[j * GT + t];
        }
        __syncthreads();

        #pragma unroll
        for (int sb = 0; sb < 2; sb++) {
            float acc[GR][4];
            #pragma unroll
            for (int r = 0; r < GR; r++)
                #pragma unroll
                for (int s = 0; s < 4; s++) acc[r][s] = 0.f;
            #pragma unroll
            for (int k = 0; k < 4; k++) {
                const int c = k * 256 + lane * 4;
                const float4 h0 = *(const float4*)(&hs[sb * 4 + 0][c]);
                const float4 h1 = *(const float4*)(&hs[sb * 4 + 1][c]);
                const float4 h2 = *(const float4*)(&hs[sb * 4 + 2][c]);
                const float4 h3 = *(const float4*)(&hs[sb * 4 + 3][c]);
                #pragma unroll
                for (int r = 0; r < GR; r++) {
                    const float4 w = wr[r][k];
                    acc[r][0] += w.x * h0.x + w.y * h0.y + w.z * h0.z + w.w * h0.w;
                    acc[r][1] += w.x * h1.x + w.y * h1.y + w.z * h1.z + w.w * h1.w;
                    acc[r][2] += w.x * h2.x + w.y * h2.y + w.z * h2.z + w.w * h2.w;
                    acc[r][3] += w.x * h3.x + w.y * h3.y + w.z * h3.z + w.w * h3.w;
                }
            }
            #pragma unroll
            for (int r = 0; r < GR; r++)
                #pragma unroll
                for (int s = 0; s < 4; s++) {
                    const float vv = wave_reduce_sum(acc[r][s]);
                    if (lane == 0) stage[sb * 4 + s][wave * GR + r] = vv;
                }
        }
        __syncthreads();
        {
            const int s = t >> 6;              // 0..7
            const int col = t & 63;
            const int sidx = chunk * GS + s;
            if (sidx >= 1) {
                const float vv = stage[s][col] + b_fc[b * 64 + col];
                out[(size_t)sidx * V + b * 64 + col] = fmaxf(vv, 0.f);
            }
        }
    }
}

// ---------------------------------------------------------------------------
// Host launcher
// ---------------------------------------------------------------------------
extern "C" void kernel_launch(void* const* d_in, const int* in_sizes, int n_in,
                              void* d_out, int out_size, void* d_ws, size_t ws_size,
                              hipStream_t stream)
{
    const int*   y     = (const int*)  d_in[0];
    const float* ctx   = (const float*)d_in[1];
    const float* w_ih0 = (const float*)d_in[2];
    const float* w_hh0 = (const float*)d_in[3];
    const float* b_ih0 = (const float*)d_in[4];
    const float* b_hh0 = (const float*)d_in[5];
    const float* w_ih1 = (const float*)d_in[6];
    const float* w_hh1 = (const float*)d_in[7];
    const float* b_ih1 = (const float*)d_in[8];
    const float* b_hh1 = (const float*)d_in[9];
    const float* w_fc  = (const float*)d_in[10];
    const float* b_fc  = (const float*)d_in[11];
    float* out = (float*)d_out;

    const size_t WQ8_BYTES  = (size_t)V * H;                 // 32,768,000
    const size_t SCL_BYTES  = (size_t)V * sizeof(float2);    // 256,000
    const size_t HIST_BYTES = (size_t)L * H * sizeof(float); // 8,388,608
    const size_t STATE_BYTES = 55296;
    const int use8 = (ws_size >= WQ8_BYTES + SCL_BYTES + HIST_BYTES + STATE_BYTES) ? 1 : 0;

    char* ws = (char*)d_ws;
    signed char* wq8     = (signed char*)ws;
    float2*      scl_eps = (float2*)(ws + WQ8_BYTES);
    float*       h1_hist = (float*)(ws + WQ8_BYTES + SCL_BYTES);
    char* base = ws + (use8 ? (WQ8_BYTES + SCL_BYTES + HIST_BYTES) : 0);
    float* v0g = (float*)(base + 0);                                // [2][4096]
    float* c0  = (float*)(base + 32768);                            // [2][1024]
    float* c1  = (float*)(base + 40960);                            // [1024]
    float* h1g = (float*)(base + 45056);                            // [2][1024]
    unsigned long long* keys = (unsigned long long*)(base + 53248); // [256]

    // out row 0 is defined as zeros
    hipMemsetAsync(d_out, 0, (size_t)V * sizeof(float), stream);

    if (use8) {
        hipMemsetAsync(h1_hist, 0, (size_t)H * sizeof(float), stream);
        quant_fc<<<512, 256, 0, stream>>>(w_fc, wq8, scl_eps);
    }

    init_kernel<<<NB, NT, 0, stream>>>(y, ctx, w_hh0, b_ih0, b_hh0,
                                       v0g, c0, c1, h1g /*buf0*/, keys);

    for (int t = 1; t < L; t++) {
        const float* v0i = v0g + ((t - 1) & 1) * G4;
        float*       v0o = v0g + (t & 1) * G4;
        const float* c0i = c0 + ((t - 1) & 1) * H;
        float*       c0o = c0 + (t & 1) * H;
        const float* h1p = h1g + ((t - 1) & 1) * H;
        float*       h1c = h1g + (t & 1) * H;
        lstm_kernel<<<NB, NT, 0, stream>>>(w_ih0, w_ih1, w_hh0, w_hh1,
                                           b_ih0, b_hh0, b_ih1, b_hh1,
                                           v0i, v0o, c0i, c0o, c1,
                                           h1p, h1c, keys,
                                           use8 ? h1_hist : (float*)nullptr, t);
        if (use8) {
            screen_kernel<<<NB, NT, 0, stream>>>(wq8, scl_eps, w_fc, b_fc,
                                                 h1c, keys);
        } else {
            fc32_kernel<<<NB, NT, 0, stream>>>(w_fc, b_fc, h1c, keys,
                                               out + (size_t)t * V);
        }
    }

    if (use8) {
        out_gemm<<<GNB, GT, 0, stream>>>(w_fc, b_fc, h1_hist, out);
    }
}